// Round 15
// baseline (62.695 us; speedup 1.0000x reference)
//
#include <hip/hip_runtime.h>

typedef __attribute__((ext_vector_type(8))) short bf16x8;
typedef __attribute__((ext_vector_type(4))) float f32x4;

#define C_DIM 512
#define HID   256
#define B_DIM 8
#define L_DIM 196
#define ROWS  14                // i-rows per wave (pair)
#define NJC   14
#define JCL   14
#define P_ELEMS (B_DIM*L_DIM*HID)
#define BLOCKS_PER_B 56         // gemm arrivals per batch
#define FUSED_BLOCKS (B_DIM*BLOCKS_PER_B)   // 448 <= co-residency capacity at lb(256,2)

// f32 -> bf16 bits, round-to-nearest (ties up)
__device__ __forceinline__ short bf16r(float x) {
  unsigned u = __builtin_bit_cast(unsigned, x);
  return (short)((u + 0x8000u) >> 16);
}

// Fused gemm -> XCD-local barrier -> pair. bid&7 = b keeps every block of
// batch b on XCD b (r12-verified +4.6us): producers and consumers share one
// L2, so the handoff needs only {vmcnt-drain + L2} not cross-XCD coherence
// (fences kept agent-scope for safety; one release + one acquire per block).
// All 448 blocks co-resident (lb(256,2): 2 blocks/CU x 256 CU = 512 >= 448),
// and every block does its gemm BEFORE spinning -> no deadlock.
__global__ __launch_bounds__(256, 2) void fused_kernel(
    const float* __restrict__ f1, const float* __restrict__ f2,
    const float* __restrict__ W1, const float* __restrict__ b1,
    const float* __restrict__ b2, const float* __restrict__ W2,
    float* __restrict__ p1, float* __restrict__ p2,
    int* __restrict__ sem, float* __restrict__ out) {
  const int b    = blockIdx.x & 7;              // XCD-co-located batch
  const int idx  = blockIdx.x >> 3;             // 0..55
  const int tid  = threadIdx.x;
  const int kq   = tid >> 6;                    // wave id (= k-quarter in gemm)
  const int lane = tid & 63;
  const int g    = lane >> 4;                   // k-subgroup 0..3
  const int mcol = lane & 15;

  // ---------------- gemm phase: one 32m x 64n tile, K-split x4 ----------------
  const int ms   = idx >> 2;                    // 0..13
  const int ntp  = idx & 3;                     // 0..3 (64-wide n tile)
  const int side = ms & 1;
  const int mt   = ms >> 1;                     // m-tile within batch, 0..6
  const float* __restrict__ f = side ? f2 : f1;
  const float* __restrict__ W = W1 + side * C_DIM * HID;
  float* __restrict__ p = side ? p2 : p1;

  int aoff[2];
  #pragma unroll
  for (int mi = 0; mi < 2; ++mi) {
    const int rib = mt * 32 + mi * 16 + mcol;   // 0..223 (tail clamped)
    const int l = rib < L_DIM ? rib : L_DIM - 1;
    aoff[mi] = (b * C_DIM) * L_DIM + l;
  }
  const int h0 = ntp * 64 + mcol;               // + ni*16

  f32x4 acc[2][4];
  #pragma unroll
  for (int mi = 0; mi < 2; ++mi)
    #pragma unroll
    for (int ni = 0; ni < 4; ++ni)
      acc[mi][ni] = (f32x4){0.f, 0.f, 0.f, 0.f};

  #pragma unroll
  for (int ks = 0; ks < 4; ++ks) {
    const int k0 = kq * 128 + ks * 32 + g * 8;  // this lane's 8 k's
    bf16x8 afr[2], bfr[4];
    #pragma unroll
    for (int mi = 0; mi < 2; ++mi) {
      const float* __restrict__ pa = f + aoff[mi] + k0 * L_DIM;
      #pragma unroll
      for (int i = 0; i < 8; ++i) afr[mi][i] = bf16r(pa[i * L_DIM]);
    }
    #pragma unroll
    for (int ni = 0; ni < 4; ++ni) {            // A shared across 4 n-frags
      const float* __restrict__ pb = W + k0 * HID + h0 + ni * 16;
      #pragma unroll
      for (int i = 0; i < 8; ++i) bfr[ni][i] = bf16r(pb[i * HID]);
    }
    #pragma unroll
    for (int mi = 0; mi < 2; ++mi)
      #pragma unroll
      for (int ni = 0; ni < 4; ++ni)
        acc[mi][ni] = __builtin_amdgcn_mfma_f32_16x16x32_bf16(
            afr[mi], bfr[ni], acc[mi][ni], 0, 0, 0);
  }

  // tree-combine 4 k-quarter waves (32 floats/lane, idx = mi*16 + ni*4 + reg)
  __shared__ float comb[2][64][33];             // 16.9 KB
  if (kq >= 2) {
    #pragma unroll
    for (int mi = 0; mi < 2; ++mi)
      #pragma unroll
      for (int ni = 0; ni < 4; ++ni)
        *(float4*)&comb[kq - 2][lane][mi * 16 + ni * 4] = *(float4*)&acc[mi][ni];
  }
  __syncthreads();
  if (kq < 2) {
    #pragma unroll
    for (int mi = 0; mi < 2; ++mi)
      #pragma unroll
      for (int ni = 0; ni < 4; ++ni) {
        const float4 o = *(const float4*)&comb[kq][lane][mi * 16 + ni * 4];
        acc[mi][ni][0] += o.x; acc[mi][ni][1] += o.y;
        acc[mi][ni][2] += o.z; acc[mi][ni][3] += o.w;
      }
  }
  __syncthreads();
  if (kq == 1) {
    #pragma unroll
    for (int mi = 0; mi < 2; ++mi)
      #pragma unroll
      for (int ni = 0; ni < 4; ++ni)
        *(float4*)&comb[0][lane][mi * 16 + ni * 4] = *(float4*)&acc[mi][ni];
  }
  __syncthreads();
  if (kq == 0) {
    // C/D layout (verified): col = lane&15, row = g*4 + reg
    #pragma unroll
    for (int mi = 0; mi < 2; ++mi) {
      const int rib0 = mt * 32 + mi * 16 + g * 4;
      #pragma unroll
      for (int ni = 0; ni < 4; ++ni) {
        const int h = h0 + ni * 16;
        const float bias = side ? 0.0f : b1[h];
        const float4 o = *(const float4*)&comb[0][lane][mi * 16 + ni * 4];
        const float v0 = acc[mi][ni][0] + o.x + bias;
        const float v1 = acc[mi][ni][1] + o.y + bias;
        const float v2 = acc[mi][ni][2] + o.z + bias;
        const float v3 = acc[mi][ni][3] + o.w + bias;
        if (rib0 + 0 < L_DIM) p[(b * L_DIM + rib0 + 0) * HID + h] = v0;
        if (rib0 + 1 < L_DIM) p[(b * L_DIM + rib0 + 1) * HID + h] = v1;
        if (rib0 + 2 < L_DIM) p[(b * L_DIM + rib0 + 2) * HID + h] = v2;
        if (rib0 + 3 < L_DIM) p[(b * L_DIM + rib0 + 3) * HID + h] = v3;
      }
    }
  }

  // out[b] init: ATOMIC store (memory-side, coherent with pair's atomicAdds
  // from other XCDs' lines sharing this cache line). Ordered before arrival.
  if (idx == 0 && tid == 0)
    __hip_atomic_store(&out[b], (float)(L_DIM * L_DIM) * b2[0],
                       __ATOMIC_RELAXED, __HIP_MEMORY_SCOPE_AGENT);

  // ---------------- per-batch arrive + spin (XCD-local) ----------------
  __syncthreads();                              // all waves' work done
  if (tid == 0) {                               // wave 0 issued ALL p-stores
    __builtin_amdgcn_fence(__ATOMIC_RELEASE, "agent");   // drain stores
    atomicAdd(&sem[b], 1);
    while (__hip_atomic_load(&sem[b], __ATOMIC_RELAXED,
                             __HIP_MEMORY_SCOPE_AGENT) < BLOCKS_PER_B)
      __builtin_amdgcn_s_sleep(2);
    __builtin_amdgcn_fence(__ATOMIC_ACQUIRE, "agent");   // L1 inv before p reads
  }
  __syncthreads();

  if (idx >= 49) return;                        // 49 pair blocks per batch

  // ---------------- pair phase (r12-exact body) ----------------
  const int r4 = idx * 4 + kq;                  // 0..195
  const int jc = r4 / ROWS;                     // 0..13
  const int wi = r4 % ROWS;                     // 0..13

  const float4 wv = *(const float4*)(W2 + lane * 4);
  const float* __restrict__ p1b = p1 + (b * L_DIM) * HID + lane * 4;

  float4 a[ROWS];
  #pragma unroll
  for (int k = 0; k < ROWS; ++k)
    a[k] = *(const float4*)(p1b + (wi + k * ROWS) * HID);  // i = wi + k*14

  float s[ROWS];
  #pragma unroll
  for (int k = 0; k < ROWS; ++k) s[k] = 0.0f;

  const float4* __restrict__ vp =
      (const float4*)(p2 + (b * L_DIM + jc * JCL) * HID) + lane;

#define PAIR_BODY(vv)                                            \
  {                                                              \
    _Pragma("unroll")                                            \
    for (int k = 0; k < ROWS; ++k) {                             \
      s[k] = fmaf(fmaxf(a[k].x + (vv).x, 0.f), wv.x, s[k]);      \
      s[k] = fmaf(fmaxf(a[k].y + (vv).y, 0.f), wv.y, s[k]);      \
      s[k] = fmaf(fmaxf(a[k].z + (vv).z, 0.f), wv.z, s[k]);      \
      s[k] = fmaf(fmaxf(a[k].w + (vv).w, 0.f), wv.w, s[k]);      \
    }                                                            \
  }

  // two 7-deep batches: 7 loads in flight, then compute
  float4 vv[7];
  #pragma unroll
  for (int j = 0; j < 7; ++j) vv[j] = vp[j * (HID / 4)];
  #pragma unroll
  for (int j = 0; j < 7; ++j) PAIR_BODY(vv[j]);
  #pragma unroll
  for (int j = 0; j < 7; ++j) vv[j] = vp[(7 + j) * (HID / 4)];
  #pragma unroll
  for (int j = 0; j < 7; ++j) PAIR_BODY(vv[j]);
#undef PAIR_BODY

  float t = 0.0f;
  #pragma unroll
  for (int k = 0; k < ROWS; ++k) t += s[k];
  #pragma unroll
  for (int off = 32; off > 0; off >>= 1) t += __shfl_down(t, off);

  __shared__ float sred[4];
  if (lane == 0) sred[kq] = t;
  __syncthreads();
  if (tid == 0)
    atomicAdd(&out[b], sred[0] + sred[1] + sred[2] + sred[3]);
}

extern "C" void kernel_launch(void* const* d_in, const int* in_sizes, int n_in,
                              void* d_out, int out_size, void* d_ws, size_t ws_size,
                              hipStream_t stream) {
  const float* f1 = (const float*)d_in[0];   // [B, C, 14, 14]
  const float* f2 = (const float*)d_in[1];
  const float* W1 = (const float*)d_in[2];   // [2C, HID]
  const float* b1 = (const float*)d_in[3];   // [HID]
  const float* W2 = (const float*)d_in[4];   // [HID, 1]
  const float* b2 = (const float*)d_in[5];   // [1]
  float* out = (float*)d_out;                // [B, 1]

  float* p1 = (float*)d_ws;
  float* p2 = p1 + P_ELEMS;
  int* sem  = (int*)(p2 + P_ELEMS);          // 8 ints

  // clear per-batch semaphores (d_ws is poisoned 0xAA once before timing)
  hipMemsetAsync(sem, 0, B_DIM * sizeof(int), stream);

  fused_kernel<<<FUSED_BLOCKS, 256, 0, stream>>>(
      f1, f2, W1, b1, b2, W2, p1, p2, sem, out);
}

// Round 16
// 24.415 us; speedup vs baseline: 2.5679x; 2.5679x over previous
//
#include <hip/hip_runtime.h>

typedef __attribute__((ext_vector_type(8))) short bf16x8;
typedef __attribute__((ext_vector_type(4))) float f32x4;

#define C_DIM 512
#define HID   256
#define B_DIM 8
#define L_DIM 196
#define GEMM_BLOCKS 448         // 8 b x 7 mt x 2 side x 4 ntp (64-wide n)
#define ROWS  14                // i-rows per wave (pair)
#define NJC   14
#define JCL   14
#define PAIR_BLOCKS ((B_DIM*NJC*ROWS)/4)    // 392 = 49*8
#define P_ELEMS (B_DIM*L_DIM*HID)

// f32 -> bf16 bits, round-to-nearest (ties up)
__device__ __forceinline__ short bf16r(float x) {
  unsigned u = __builtin_bit_cast(unsigned, x);
  return (short)((u + 0x8000u) >> 16);
}

// Phase 1 (r15's gemm phase, standalone): MFMA bf16, K-split x4, XCD-local.
//   p[b,l,h] = sum_c f[b,c,l] * W[c,h]   (+ b1[h] for side 0)
// bid&7 = b -> all blocks of batch b on XCD b. Block = one 32m x 64n tile;
// A-fragments shared across 4 n-frags (halved f re-gathers vs 32-wide r12).
__global__ __launch_bounds__(256) void gemm_p_mfma(
    const float* __restrict__ f1, const float* __restrict__ f2,
    const float* __restrict__ W1, const float* __restrict__ b1,
    const float* __restrict__ b2,
    float* __restrict__ p1, float* __restrict__ p2,
    float* __restrict__ out) {
  // init output accumulators (pair_kernel atomicAdds into them)
  if (blockIdx.x == 0 && threadIdx.x < B_DIM)
    out[threadIdx.x] = (float)(L_DIM * L_DIM) * b2[0];

  const int b    = blockIdx.x & 7;              // XCD-co-located batch
  const int idx  = blockIdx.x >> 3;             // 0..55
  const int ms   = idx >> 2;                    // 0..13
  const int ntp  = idx & 3;                     // 0..3 (64-wide n tile)
  const int side = ms & 1;
  const int mt   = ms >> 1;                     // m-tile within batch, 0..6

  const float* __restrict__ f = side ? f2 : f1;
  const float* __restrict__ W = W1 + side * C_DIM * HID;
  float* __restrict__ p = side ? p2 : p1;

  const int tid  = threadIdx.x;
  const int kq   = tid >> 6;                    // wave = k-quarter 0..3
  const int lane = tid & 63;
  const int g    = lane >> 4;                   // k-subgroup 0..3
  const int mcol = lane & 15;

  int aoff[2];
  #pragma unroll
  for (int mi = 0; mi < 2; ++mi) {
    const int rib = mt * 32 + mi * 16 + mcol;   // 0..223 (tail clamped)
    const int l = rib < L_DIM ? rib : L_DIM - 1;
    aoff[mi] = (b * C_DIM) * L_DIM + l;
  }
  const int h0 = ntp * 64 + mcol;               // + ni*16

  f32x4 acc[2][4];
  #pragma unroll
  for (int mi = 0; mi < 2; ++mi)
    #pragma unroll
    for (int ni = 0; ni < 4; ++ni)
      acc[mi][ni] = (f32x4){0.f, 0.f, 0.f, 0.f};

  #pragma unroll
  for (int ks = 0; ks < 4; ++ks) {
    const int k0 = kq * 128 + ks * 32 + g * 8;  // this lane's 8 k's
    bf16x8 afr[2], bfr[4];
    #pragma unroll
    for (int mi = 0; mi < 2; ++mi) {
      const float* __restrict__ pa = f + aoff[mi] + k0 * L_DIM;
      #pragma unroll
      for (int i = 0; i < 8; ++i) afr[mi][i] = bf16r(pa[i * L_DIM]);
    }
    #pragma unroll
    for (int ni = 0; ni < 4; ++ni) {            // A shared across 4 n-frags
      const float* __restrict__ pb = W + k0 * HID + h0 + ni * 16;
      #pragma unroll
      for (int i = 0; i < 8; ++i) bfr[ni][i] = bf16r(pb[i * HID]);
    }
    #pragma unroll
    for (int mi = 0; mi < 2; ++mi)
      #pragma unroll
      for (int ni = 0; ni < 4; ++ni)
        acc[mi][ni] = __builtin_amdgcn_mfma_f32_16x16x32_bf16(
            afr[mi], bfr[ni], acc[mi][ni], 0, 0, 0);
  }

  // tree-combine 4 k-quarter waves (32 floats/lane, idx = mi*16 + ni*4 + reg)
  __shared__ float comb[2][64][33];             // 16.9 KB
  if (kq >= 2) {
    #pragma unroll
    for (int mi = 0; mi < 2; ++mi)
      #pragma unroll
      for (int ni = 0; ni < 4; ++ni)
        *(float4*)&comb[kq - 2][lane][mi * 16 + ni * 4] = *(float4*)&acc[mi][ni];
  }
  __syncthreads();
  if (kq < 2) {
    #pragma unroll
    for (int mi = 0; mi < 2; ++mi)
      #pragma unroll
      for (int ni = 0; ni < 4; ++ni) {
        const float4 o = *(const float4*)&comb[kq][lane][mi * 16 + ni * 4];
        acc[mi][ni][0] += o.x; acc[mi][ni][1] += o.y;
        acc[mi][ni][2] += o.z; acc[mi][ni][3] += o.w;
      }
  }
  __syncthreads();
  if (kq == 1) {
    #pragma unroll
    for (int mi = 0; mi < 2; ++mi)
      #pragma unroll
      for (int ni = 0; ni < 4; ++ni)
        *(float4*)&comb[0][lane][mi * 16 + ni * 4] = *(float4*)&acc[mi][ni];
  }
  __syncthreads();
  if (kq == 0) {
    // C/D layout (verified): col = lane&15, row = g*4 + reg
    #pragma unroll
    for (int mi = 0; mi < 2; ++mi) {
      const int rib0 = mt * 32 + mi * 16 + g * 4;
      #pragma unroll
      for (int ni = 0; ni < 4; ++ni) {
        const int h = h0 + ni * 16;
        const float bias = side ? 0.0f : b1[h];
        const float4 o = *(const float4*)&comb[0][lane][mi * 16 + ni * 4];
        const float v0 = acc[mi][ni][0] + o.x + bias;
        const float v1 = acc[mi][ni][1] + o.y + bias;
        const float v2 = acc[mi][ni][2] + o.z + bias;
        const float v3 = acc[mi][ni][3] + o.w + bias;
        if (rib0 + 0 < L_DIM) p[(b * L_DIM + rib0 + 0) * HID + h] = v0;
        if (rib0 + 1 < L_DIM) p[(b * L_DIM + rib0 + 1) * HID + h] = v1;
        if (rib0 + 2 < L_DIM) p[(b * L_DIM + rib0 + 2) * HID + h] = v2;
        if (rib0 + 3 < L_DIM) p[(b * L_DIM + rib0 + 3) * HID + h] = v3;
      }
    }
  }
}

// Phase 2 (r12 exact): wgid = idx*8 + b -> XCD-local; wave = 14 i x 14 j;
// block-sum -> ONE atomicAdd into out[b].
__global__ __launch_bounds__(256) void pair_kernel(
    const float* __restrict__ p1, const float* __restrict__ p2,
    const float* __restrict__ W2, float* __restrict__ out) {
  const int lane = threadIdx.x & 63;
  const int w    = threadIdx.x >> 6;
  const int b    = blockIdx.x & 7;              // XCD-co-located batch
  const int idx  = blockIdx.x >> 3;             // 0..48
  const int r4   = idx * 4 + w;                 // 0..195
  const int jc   = r4 / ROWS;                   // 0..13
  const int wi   = r4 % ROWS;                   // 0..13

  const float4 wv = *(const float4*)(W2 + lane * 4);
  const float* __restrict__ p1b = p1 + (b * L_DIM) * HID + lane * 4;

  float4 a[ROWS];
  #pragma unroll
  for (int k = 0; k < ROWS; ++k)
    a[k] = *(const float4*)(p1b + (wi + k * ROWS) * HID);  // i = wi + k*14

  float s[ROWS];
  #pragma unroll
  for (int k = 0; k < ROWS; ++k) s[k] = 0.0f;

  const float4* __restrict__ vp =
      (const float4*)(p2 + (b * L_DIM + jc * JCL) * HID) + lane;

#define PAIR_BODY(vv)                                            \
  {                                                              \
    _Pragma("unroll")                                            \
    for (int k = 0; k < ROWS; ++k) {                             \
      s[k] = fmaf(fmaxf(a[k].x + (vv).x, 0.f), wv.x, s[k]);      \
      s[k] = fmaf(fmaxf(a[k].y + (vv).y, 0.f), wv.y, s[k]);      \
      s[k] = fmaf(fmaxf(a[k].z + (vv).z, 0.f), wv.z, s[k]);      \
      s[k] = fmaf(fmaxf(a[k].w + (vv).w, 0.f), wv.w, s[k]);      \
    }                                                            \
  }

  // two 7-deep batches: 7 loads in flight, then compute
  float4 vv[7];
  #pragma unroll
  for (int j = 0; j < 7; ++j) vv[j] = vp[j * (HID / 4)];
  #pragma unroll
  for (int j = 0; j < 7; ++j) PAIR_BODY(vv[j]);
  #pragma unroll
  for (int j = 0; j < 7; ++j) vv[j] = vp[(7 + j) * (HID / 4)];
  #pragma unroll
  for (int j = 0; j < 7; ++j) PAIR_BODY(vv[j]);
#undef PAIR_BODY

  // collapse rows (13 adds), then one 6-step wave reduce
  float t = 0.0f;
  #pragma unroll
  for (int k = 0; k < ROWS; ++k) t += s[k];
  #pragma unroll
  for (int off = 32; off > 0; off >>= 1) t += __shfl_down(t, off);

  __shared__ float sred[4];
  if (lane == 0) sred[w] = t;
  __syncthreads();
  if (threadIdx.x == 0)
    atomicAdd(&out[b], sred[0] + sred[1] + sred[2] + sred[3]);  // 392 total
}

extern "C" void kernel_launch(void* const* d_in, const int* in_sizes, int n_in,
                              void* d_out, int out_size, void* d_ws, size_t ws_size,
                              hipStream_t stream) {
  const float* f1 = (const float*)d_in[0];   // [B, C, 14, 14]
  const float* f2 = (const float*)d_in[1];
  const float* W1 = (const float*)d_in[2];   // [2C, HID]
  const float* b1 = (const float*)d_in[3];   // [HID]
  const float* W2 = (const float*)d_in[4];   // [HID, 1]
  const float* b2 = (const float*)d_in[5];   // [1]
  float* out = (float*)d_out;                // [B, 1]

  float* p1 = (float*)d_ws;
  float* p2 = p1 + P_ELEMS;

  gemm_p_mfma<<<GEMM_BLOCKS, 256, 0, stream>>>(f1, f2, W1, b1, b2, p1, p2, out);

  pair_kernel<<<PAIR_BLOCKS, 256, 0, stream>>>(p1, p2, W2, out);
}